// Round 10
// baseline (58.045 us; speedup 1.0000x reference)
//
#include <hip/hip_runtime.h>
#include <hip/hip_bf16.h>

#define NEG_BIG -1000000.0f

typedef __attribute__((ext_vector_type(8))) short short8;
typedef __attribute__((ext_vector_type(4))) short short4v;
typedef __attribute__((ext_vector_type(4))) float floatx4;

#if __has_builtin(__builtin_amdgcn_exp2f)
#define EXP2F(x) __builtin_amdgcn_exp2f(x)
#else
#define EXP2F(x) exp2f(x)
#endif

// K=16 bf16 MFMA (PV step): A[row=lane&15][k=4*(lane>>4)+j]
#if __has_builtin(__builtin_amdgcn_mfma_f32_16x16x16bf16_1k)
#define MFMA16(a, b, c) __builtin_amdgcn_mfma_f32_16x16x16bf16_1k(a, b, c, 0, 0, 0)
#else
static __device__ __forceinline__ floatx4 MFMA16_fn(short4v a, short4v b, floatx4 c) {
    floatx4 d;
    asm("v_mfma_f32_16x16x16_bf16 %0, %1, %2, %3\n\ts_nop 4"
        : "=v"(d) : "v"(a), "v"(b), "v"(c));
    return d;
}
#define MFMA16(a, b, c) MFMA16_fn(a, b, c)
#endif

// xor16 + xor32 wave reduction on the VALU (permlane swaps).
#if __has_builtin(__builtin_amdgcn_permlane16_swap) && __has_builtin(__builtin_amdgcn_permlane32_swap)
static __device__ __forceinline__ float redmax16_32(float x) {
    auto a = __builtin_amdgcn_permlane16_swap(__float_as_int(x), __float_as_int(x), false, false);
    x = fmaxf(__int_as_float(a[0]), __int_as_float(a[1]));
    auto b = __builtin_amdgcn_permlane32_swap(__float_as_int(x), __float_as_int(x), false, false);
    return fmaxf(__int_as_float(b[0]), __int_as_float(b[1]));
}
static __device__ __forceinline__ float redsum16_32(float x) {
    auto a = __builtin_amdgcn_permlane16_swap(__float_as_int(x), __float_as_int(x), false, false);
    x = __int_as_float(a[0]) + __int_as_float(a[1]);
    auto b = __builtin_amdgcn_permlane32_swap(__float_as_int(x), __float_as_int(x), false, false);
    return __int_as_float(b[0]) + __int_as_float(b[1]);
}
#else
static __device__ __forceinline__ float redmax16_32(float x) {
    x = fmaxf(x, __shfl_xor(x, 16));
    return fmaxf(x, __shfl_xor(x, 32));
}
static __device__ __forceinline__ float redsum16_32(float x) {
    x += __shfl_xor(x, 16);
    return x + __shfl_xor(x, 32);
}
#endif

static __device__ __forceinline__ unsigned short bf16u(float f) {
    union { __hip_bfloat16 h; unsigned short u; } c;
    c.h = __float2bfloat16(f);
    return c.u;
}

static __device__ __forceinline__ short8 pack8(float4 a, float4 b) {
    union { short8 s; __hip_bfloat162 h[4]; } u;
    u.h[0] = __float22bfloat162_rn(make_float2(a.x, a.y));
    u.h[1] = __float22bfloat162_rn(make_float2(a.z, a.w));
    u.h[2] = __float22bfloat162_rn(make_float2(b.x, b.y));
    u.h[3] = __float22bfloat162_rn(make_float2(b.z, b.w));
    return u.s;
}

// Block: 256 thr = 4 waves, 64 q-rows. Grid: 1024 blocks, XCD-swizzled,
// launch_bounds(256,4) + 40 KB LDS -> 4 blocks/CU, whole grid co-resident.
// SOFTWARE-PIPELINED tiles: iteration t runs QK^T(t) (MFMA, independent)
// concurrently with softmax(t-1)+PV(t-1) (dependent VALU chain) on the
// register-carried score tile sp[]. V is TRIPLE-buffered (PV(t-1) reads
// buf (t-1)%3 while staging writes (t+1)%3); K double-buffered.
// Swapped QK^T (lane-local softmax, in-register P), permlane reductions,
// deferred rescale (THR=11, exp2 domain), one barrier per tile.
__global__ __launch_bounds__(256, 4)
void attn_fwd(const float* __restrict__ Q, const float* __restrict__ K,
              const float* __restrict__ V, const int* __restrict__ vlen,
              float* __restrict__ out)
{
    // K_lds: elem (row,col) at row*64 + (col ^ ((row&7)*8))
    __shared__ __attribute__((aligned(16))) unsigned short K_lds[2][4096];
    // VT_lds: elem (dv,k) at dv*64 + (k ^ (((dv&7) ^ (dv>>3)) * 8))
    __shared__ __attribute__((aligned(16))) unsigned short VT_lds[3][4096];

    const int bid  = blockIdx.x;
    const int orig = (bid & 7) * 128 + (bid >> 3);  // bijective (1024%8==0)
    const int b    = orig >> 4;
    const int qc   = orig & 15;

    const int tid = threadIdx.x;
    const int l   = tid & 63;
    const int w   = tid >> 6;
    const int lr  = l & 15;
    const int lg  = l >> 4;

    const float* Qb = Q + (size_t)b * 65536;
    const float* Kb = K + (size_t)b * 65536;
    const float* Vb = V + (size_t)b * 65536;

    const int valid = vlen[b];
    const int kmax  = (valid == 0) ? 1024 : valid;   // all-masked -> uniform
    const int ntile = (kmax + 63) >> 6;

    // Q fragments (B-operand of swapped QK^T), pre-scaled log2(e)/8
    const float qscale = 0.18033688011112042f;
    short8 qf[2];
#pragma unroll
    for (int c = 0; c < 2; ++c) {
        const float* p = Qb + (size_t)(qc*64 + w*16 + lr) * 64 + c*32 + lg*8;
        float4 a = *(const float4*)p, bb = *(const float4*)(p + 4);
        a.x *= qscale; a.y *= qscale; a.z *= qscale; a.w *= qscale;
        bb.x *= qscale; bb.y *= qscale; bb.z *= qscale; bb.w *= qscale;
        qf[c] = pack8(a, bb);
    }

    floatx4 o[4];
#pragma unroll
    for (int n = 0; n < 4; ++n) o[n] = (floatx4){0.f, 0.f, 0.f, 0.f};
    float m = -INFINITY, lsum = 0.f;      // scalar state for q-row lr

    // per-wave staging: wave w stages tile rows [w*16, w*16+16)
    const int row   = w * 16 + (l >> 2);  // 0..63
    const int cbase = (l & 3) * 16;       // col quarter (floats)

    float4 kra[4], vra[4];

#define LOAD_K(T) do {                                                      \
    const float* pk_ = Kb + (size_t)((T)*64 + row) * 64 + cbase;            \
    kra[0] = *(const float4*)pk_;       kra[1] = *(const float4*)(pk_ + 4); \
    kra[2] = *(const float4*)(pk_ + 8); kra[3] = *(const float4*)(pk_ + 12);\
    } while (0)

#define LOAD_V(T) do {                                                      \
    const float* pv_ = Vb + (size_t)((T)*64 + row) * 64 + cbase;            \
    vra[0] = *(const float4*)pv_;       vra[1] = *(const float4*)(pv_ + 4); \
    vra[2] = *(const float4*)(pv_ + 8); vra[3] = *(const float4*)(pv_ + 12);\
    } while (0)

#define WRITE_K(B) do {                                                     \
    const int _fk = (row & 7) * 8;                                          \
    *(short8*)&K_lds[B][row*64 + (cbase ^ _fk)]       = pack8(kra[0], kra[1]); \
    *(short8*)&K_lds[B][row*64 + ((cbase + 8) ^ _fk)] = pack8(kra[2], kra[3]); \
    } while (0)

#define WRITE_V(B) do {                                                     \
    _Pragma("unroll")                                                       \
    for (int j = 0; j < 16; ++j) {                                          \
        const int dv = cbase + j;                                           \
        const int fv = ((dv & 7) ^ (dv >> 3)) * 8;                          \
        VT_lds[B][dv*64 + (row ^ fv)] = bf16u(((const float*)&vra[j>>2])[j&3]); \
    } } while (0)

// QK^T of tile T from K buffer KBUF into SA, then mask.
#define QK_COMPUTE(SA, KBUF, T) do {                                        \
    const int _k0 = (T) * 64;                                               \
    __builtin_amdgcn_s_setprio(1);                                          \
    _Pragma("unroll")                                                       \
    for (int n = 0; n < 4; ++n) {                                           \
        const int kr_ = n*16 + lr;                                          \
        const int fk_ = (lr & 7) * 8;                                       \
        const short8 kf0 = *(const short8*)&K_lds[KBUF][kr_*64 + ((lg*8)      ^ fk_)]; \
        const short8 kf1 = *(const short8*)&K_lds[KBUF][kr_*64 + ((32 + lg*8) ^ fk_)]; \
        SA[n] = (floatx4){0.f, 0.f, 0.f, 0.f};                              \
        SA[n] = __builtin_amdgcn_mfma_f32_16x16x32_bf16(kf0, qf[0], SA[n], 0, 0, 0); \
        SA[n] = __builtin_amdgcn_mfma_f32_16x16x32_bf16(kf1, qf[1], SA[n], 0, 0, 0); \
    }                                                                       \
    __builtin_amdgcn_s_setprio(0);                                          \
    if ((_k0 + 64) > valid) {                                               \
        const int kb_ = _k0 + lg*4;                                         \
        _Pragma("unroll")                                                   \
        for (int n = 0; n < 4; ++n)                                         \
        _Pragma("unroll")                                                   \
        for (int r = 0; r < 4; ++r)                                         \
            SA[n][r] = (kb_ + n*16 + r >= valid) ? NEG_BIG : SA[n][r];      \
    } } while (0)

// Online softmax on SA (in place -> P) + PV accumulate from VT_lds[VBUF].
#define SOFTMAX_PV(SA, VBUF) do {                                           \
    float rmax = fmaxf(                                                     \
        fmaxf(fmaxf(fmaxf(SA[0][0], SA[0][1]), fmaxf(SA[0][2], SA[0][3])),  \
              fmaxf(fmaxf(SA[1][0], SA[1][1]), fmaxf(SA[1][2], SA[1][3]))), \
        fmaxf(fmaxf(fmaxf(SA[2][0], SA[2][1]), fmaxf(SA[2][2], SA[2][3])),  \
              fmaxf(fmaxf(SA[3][0], SA[3][1]), fmaxf(SA[3][2], SA[3][3])))); \
    rmax = redmax16_32(rmax);                                               \
    if (!__all(rmax <= m + 11.0f)) {                                        \
        const float nm_ = fmaxf(m, rmax);                                   \
        const float sc_f = EXP2F(m - nm_);                                  \
        m = nm_;                                                            \
        lsum *= sc_f;                                                       \
        float sc_r[4];                                                      \
        _Pragma("unroll")                                                   \
        for (int r = 0; r < 4; ++r) sc_r[r] = __shfl(sc_f, lg*4 + r);       \
        _Pragma("unroll")                                                   \
        for (int n = 0; n < 4; ++n)                                         \
        _Pragma("unroll")                                                   \
        for (int r = 0; r < 4; ++r) o[n][r] *= sc_r[r];                     \
    }                                                                       \
    float rs = 0.f;                                                         \
    _Pragma("unroll")                                                       \
    for (int n = 0; n < 4; ++n)                                             \
    _Pragma("unroll")                                                       \
    for (int r = 0; r < 4; ++r) {                                           \
        SA[n][r] = EXP2F(SA[n][r] - m);                                     \
        rs += SA[n][r];                                                     \
    }                                                                       \
    lsum += redsum16_32(rs);                                                \
    short4v pkf[4];                                                         \
    _Pragma("unroll")                                                       \
    for (int n = 0; n < 4; ++n) {                                           \
        union { short4v s; __hip_bfloat162 h[2]; } u;                       \
        u.h[0] = __float22bfloat162_rn(make_float2(SA[n][0], SA[n][1]));    \
        u.h[1] = __float22bfloat162_rn(make_float2(SA[n][2], SA[n][3]));    \
        pkf[n] = u.s;                                                       \
    }                                                                       \
    __builtin_amdgcn_s_setprio(1);                                          \
    _Pragma("unroll")                                                       \
    for (int kc = 0; kc < 4; ++kc) {                                        \
        _Pragma("unroll")                                                   \
        for (int n2 = 0; n2 < 4; ++n2) {                                    \
            const int dv_ = n2*16 + lr;                                     \
            const int fv_ = ((dv_ & 7) ^ (dv_ >> 3)) * 8;                   \
            const short4v vf = *(const short4v*)&VT_lds[VBUF][dv_*64 + ((kc*16 + lg*4) ^ fv_)]; \
            o[n2] = MFMA16(pkf[kc], vf, o[n2]);                             \
        }                                                                   \
    }                                                                       \
    __builtin_amdgcn_s_setprio(0);                                          \
    } while (0)

    // ---- prologue: stage tile 0; QK(0) while tile 1 stages ----
    LOAD_K(0);
    LOAD_V(0);
    WRITE_K(0);
    WRITE_V(0);
    __syncthreads();

    floatx4 sp[4];                       // carried score tile (t-1)
    if (ntile > 1) { LOAD_K(1); LOAD_V(1); }
    QK_COMPUTE(sp, 0, 0);
    if (ntile > 1) {
        WRITE_K(1);
        WRITE_V(1);
        __syncthreads();
    }

    int vr = 0, vw = 2;                  // V buf of tile t-1 / tile t+1
    for (int t = 1; t < ntile; ++t) {
        const bool pf = (t + 1 < ntile);
        if (pf) { LOAD_K(t + 1); LOAD_V(t + 1); }

        floatx4 sc[4];
        QK_COMPUTE(sc, t & 1, t);        // MFMA work, independent of sp chain
        SOFTMAX_PV(sp, vr);              // dependent VALU chain of tile t-1

        if (pf) { WRITE_K((t + 1) & 1); WRITE_V(vw); }
        __syncthreads();                 // one barrier per tile

#pragma unroll
        for (int n = 0; n < 4; ++n) sp[n] = sc[n];
        vr = (vr == 2) ? 0 : vr + 1;
        vw = (vw == 2) ? 0 : vw + 1;
    }

    // ---- finish last tile ----
    SOFTMAX_PV(sp, vr);

    // ---- epilogue: normalize and store (coalesced) ----
    const float inv = 1.0f / lsum;
    float inv_r[4];
#pragma unroll
    for (int r = 0; r < 4; ++r) inv_r[r] = __shfl(inv, lg*4 + r);

    float* Ob = out + (size_t)b * 65536;
#pragma unroll
    for (int n = 0; n < 4; ++n)
#pragma unroll
    for (int r = 0; r < 4; ++r) {
        const int q = qc*64 + w*16 + lg*4 + r;
        Ob[(size_t)q * 64 + n*16 + lr] = o[n][r] * inv_r[r];
    }
#undef LOAD_K
#undef LOAD_V
#undef WRITE_K
#undef WRITE_V
#undef QK_COMPUTE
#undef SOFTMAX_PV
}

extern "C" void kernel_launch(void* const* d_in, const int* in_sizes, int n_in,
                              void* d_out, int out_size, void* d_ws, size_t ws_size,
                              hipStream_t stream) {
    (void)in_sizes; (void)n_in; (void)d_ws; (void)ws_size; (void)out_size;
    const float* Q  = (const float*)d_in[0];
    const float* K  = (const float*)d_in[1];
    const float* V  = (const float*)d_in[2];
    const int*   vl = (const int*)d_in[3];
    float* O = (float*)d_out;
    attn_fwd<<<dim3(1024), dim3(256), 0, stream>>>(Q, K, V, vl, O);
}

// Round 11
// 44.542 us; speedup vs baseline: 1.3031x; 1.3031x over previous
//
#include <hip/hip_runtime.h>
#include <hip/hip_bf16.h>

#define NEG_BIG -1000000.0f

typedef __attribute__((ext_vector_type(8))) short short8;
typedef __attribute__((ext_vector_type(4))) short short4v;
typedef __attribute__((ext_vector_type(4))) float floatx4;

#if __has_builtin(__builtin_amdgcn_exp2f)
#define EXP2F(x) __builtin_amdgcn_exp2f(x)
#else
#define EXP2F(x) exp2f(x)
#endif

// K=16 bf16 MFMA (PV step): A[row=lane&15][k=4*(lane>>4)+j]
#if __has_builtin(__builtin_amdgcn_mfma_f32_16x16x16bf16_1k)
#define MFMA16(a, b, c) __builtin_amdgcn_mfma_f32_16x16x16bf16_1k(a, b, c, 0, 0, 0)
#else
static __device__ __forceinline__ floatx4 MFMA16_fn(short4v a, short4v b, floatx4 c) {
    floatx4 d;
    asm("v_mfma_f32_16x16x16_bf16 %0, %1, %2, %3\n\ts_nop 4"
        : "=v"(d) : "v"(a), "v"(b), "v"(c));
    return d;
}
#define MFMA16(a, b, c) MFMA16_fn(a, b, c)
#endif

// xor16 + xor32 wave reduction on the VALU (permlane swaps).
#if __has_builtin(__builtin_amdgcn_permlane16_swap) && __has_builtin(__builtin_amdgcn_permlane32_swap)
static __device__ __forceinline__ float redmax16_32(float x) {
    auto a = __builtin_amdgcn_permlane16_swap(__float_as_int(x), __float_as_int(x), false, false);
    x = fmaxf(__int_as_float(a[0]), __int_as_float(a[1]));
    auto b = __builtin_amdgcn_permlane32_swap(__float_as_int(x), __float_as_int(x), false, false);
    return fmaxf(__int_as_float(b[0]), __int_as_float(b[1]));
}
static __device__ __forceinline__ float redsum16_32(float x) {
    auto a = __builtin_amdgcn_permlane16_swap(__float_as_int(x), __float_as_int(x), false, false);
    x = __int_as_float(a[0]) + __int_as_float(a[1]);
    auto b = __builtin_amdgcn_permlane32_swap(__float_as_int(x), __float_as_int(x), false, false);
    return __int_as_float(b[0]) + __int_as_float(b[1]);
}
#else
static __device__ __forceinline__ float redmax16_32(float x) {
    x = fmaxf(x, __shfl_xor(x, 16));
    return fmaxf(x, __shfl_xor(x, 32));
}
static __device__ __forceinline__ float redsum16_32(float x) {
    x += __shfl_xor(x, 16);
    return x + __shfl_xor(x, 32);
}
#endif

static __device__ __forceinline__ unsigned short bf16u(float f) {
    union { __hip_bfloat16 h; unsigned short u; } c;
    c.h = __float2bfloat16(f);
    return c.u;
}

static __device__ __forceinline__ short8 pack8(float4 a, float4 b) {
    union { short8 s; __hip_bfloat162 h[4]; } u;
    u.h[0] = __float22bfloat162_rn(make_float2(a.x, a.y));
    u.h[1] = __float22bfloat162_rn(make_float2(a.z, a.w));
    u.h[2] = __float22bfloat162_rn(make_float2(b.x, b.y));
    u.h[3] = __float22bfloat162_rn(make_float2(b.z, b.w));
    return u.s;
}

// Block: 256 thr = 4 waves, 64 q-rows. Grid: 1024 blocks, XCD-swizzled,
// launch_bounds(256,4) + 40 KB LDS -> 4 blocks/CU, whole grid co-resident.
// PV-DEFERRED PIPELINE: iteration t runs PV(t-1) (from carried bf16 P
// fragments pkp[], 8 VGPRs) INTERLEAVED with QK^T(t) in one MFMA region
// (fully independent), then softmax(t) -> new pkp. Serial chain per tile
// shrinks from QK+SM+PV to QK+SM. V triple-buffered (PV reads (t-1)%3,
// staging writes (t+1)%3); K double-buffered. r10's f32-score carry (32
// regs) spilled at the 128-cap; this carries 8 regs.
__global__ __launch_bounds__(256, 4)
void attn_fwd(const float* __restrict__ Q, const float* __restrict__ K,
              const float* __restrict__ V, const int* __restrict__ vlen,
              float* __restrict__ out)
{
    // K_lds: elem (row,col) at row*64 + (col ^ ((row&7)*8))
    __shared__ __attribute__((aligned(16))) unsigned short K_lds[2][4096];
    // VT_lds: elem (dv,k) at dv*64 + (k ^ (((dv&7) ^ (dv>>3)) * 8))
    __shared__ __attribute__((aligned(16))) unsigned short VT_lds[3][4096];

    const int bid  = blockIdx.x;
    const int orig = (bid & 7) * 128 + (bid >> 3);  // bijective (1024%8==0)
    const int b    = orig >> 4;
    const int qc   = orig & 15;

    const int tid = threadIdx.x;
    const int l   = tid & 63;
    const int w   = tid >> 6;
    const int lr  = l & 15;
    const int lg  = l >> 4;

    const float* Qb = Q + (size_t)b * 65536;
    const float* Kb = K + (size_t)b * 65536;
    const float* Vb = V + (size_t)b * 65536;

    const int valid = vlen[b];
    const int kmax  = (valid == 0) ? 1024 : valid;   // all-masked -> uniform
    const int ntile = (kmax + 63) >> 6;

    // Q fragments (B-operand of swapped QK^T), pre-scaled log2(e)/8
    const float qscale = 0.18033688011112042f;
    short8 qf[2];
#pragma unroll
    for (int c = 0; c < 2; ++c) {
        const float* p = Qb + (size_t)(qc*64 + w*16 + lr) * 64 + c*32 + lg*8;
        float4 a = *(const float4*)p, bb = *(const float4*)(p + 4);
        a.x *= qscale; a.y *= qscale; a.z *= qscale; a.w *= qscale;
        bb.x *= qscale; bb.y *= qscale; bb.z *= qscale; bb.w *= qscale;
        qf[c] = pack8(a, bb);
    }

    floatx4 o[4];
#pragma unroll
    for (int n = 0; n < 4; ++n) o[n] = (floatx4){0.f, 0.f, 0.f, 0.f};
    float m = -INFINITY, lsum = 0.f;      // scalar state for q-row lr
    short4v pkp[4];                       // carried bf16 P frags of tile t-1

    // per-wave staging: wave w stages tile rows [w*16, w*16+16)
    const int row   = w * 16 + (l >> 2);  // 0..63
    const int cbase = (l & 3) * 16;       // col quarter (floats)

    float4 kra[4], vra[4];

#define LOAD_K(T) do {                                                      \
    const float* pk_ = Kb + (size_t)((T)*64 + row) * 64 + cbase;            \
    kra[0] = *(const float4*)pk_;       kra[1] = *(const float4*)(pk_ + 4); \
    kra[2] = *(const float4*)(pk_ + 8); kra[3] = *(const float4*)(pk_ + 12);\
    } while (0)

#define LOAD_V(T) do {                                                      \
    const float* pv_ = Vb + (size_t)((T)*64 + row) * 64 + cbase;            \
    vra[0] = *(const float4*)pv_;       vra[1] = *(const float4*)(pv_ + 4); \
    vra[2] = *(const float4*)(pv_ + 8); vra[3] = *(const float4*)(pv_ + 12);\
    } while (0)

#define WRITE_K(B) do {                                                     \
    const int _fk = (row & 7) * 8;                                          \
    *(short8*)&K_lds[B][row*64 + (cbase ^ _fk)]       = pack8(kra[0], kra[1]); \
    *(short8*)&K_lds[B][row*64 + ((cbase + 8) ^ _fk)] = pack8(kra[2], kra[3]); \
    } while (0)

#define WRITE_V(B) do {                                                     \
    _Pragma("unroll")                                                       \
    for (int j = 0; j < 16; ++j) {                                          \
        const int dv = cbase + j;                                           \
        const int fv = ((dv & 7) ^ (dv >> 3)) * 8;                          \
        VT_lds[B][dv*64 + (row ^ fv)] = bf16u(((const float*)&vra[j>>2])[j&3]); \
    } } while (0)

// QK^T of tile T from K buffer KBUF into SA (no mask).
#define QK_MFMA(SA, KBUF) do {                                              \
    _Pragma("unroll")                                                       \
    for (int n = 0; n < 4; ++n) {                                           \
        const int kr_ = n*16 + lr;                                          \
        const int fk_ = (lr & 7) * 8;                                       \
        const short8 kf0 = *(const short8*)&K_lds[KBUF][kr_*64 + ((lg*8)      ^ fk_)]; \
        const short8 kf1 = *(const short8*)&K_lds[KBUF][kr_*64 + ((32 + lg*8) ^ fk_)]; \
        SA[n] = (floatx4){0.f, 0.f, 0.f, 0.f};                              \
        SA[n] = __builtin_amdgcn_mfma_f32_16x16x32_bf16(kf0, qf[0], SA[n], 0, 0, 0); \
        SA[n] = __builtin_amdgcn_mfma_f32_16x16x32_bf16(kf1, qf[1], SA[n], 0, 0, 0); \
    } } while (0)

// PV accumulate of the CARRIED tile from VT_lds[VBUF].
#define PV_MFMA(VBUF) do {                                                  \
    _Pragma("unroll")                                                       \
    for (int kc = 0; kc < 4; ++kc) {                                        \
        _Pragma("unroll")                                                   \
        for (int n2 = 0; n2 < 4; ++n2) {                                    \
            const int dv_ = n2*16 + lr;                                     \
            const int fv_ = ((dv_ & 7) ^ (dv_ >> 3)) * 8;                   \
            const short4v vf = *(const short4v*)&VT_lds[VBUF][dv_*64 + ((kc*16 + lg*4) ^ fv_)]; \
            o[n2] = MFMA16(pkp[kc], vf, o[n2]);                             \
        }                                                                   \
    } } while (0)

// mask + online softmax on SA (exp2 domain, deferred rescale) -> new pkp
#define SOFTMAX(SA, T) do {                                                 \
    const int _k0 = (T) * 64;                                               \
    if ((_k0 + 64) > valid) {                                               \
        const int kb_ = _k0 + lg*4;                                         \
        _Pragma("unroll")                                                   \
        for (int n = 0; n < 4; ++n)                                         \
        _Pragma("unroll")                                                   \
        for (int r = 0; r < 4; ++r)                                         \
            SA[n][r] = (kb_ + n*16 + r >= valid) ? NEG_BIG : SA[n][r];      \
    }                                                                       \
    /* balanced max tree (max3-fusable) */                                  \
    float m0_ = fmaxf(fmaxf(SA[0][0], SA[0][1]), SA[0][2]);                 \
    float m1_ = fmaxf(fmaxf(SA[0][3], SA[1][0]), SA[1][1]);                 \
    float m2_ = fmaxf(fmaxf(SA[1][2], SA[1][3]), SA[2][0]);                 \
    float m3_ = fmaxf(fmaxf(SA[2][1], SA[2][2]), SA[2][3]);                 \
    float m4_ = fmaxf(fmaxf(SA[3][0], SA[3][1]), SA[3][2]);                 \
    float rmax = fmaxf(fmaxf(fmaxf(m0_, m1_), fmaxf(m2_, m3_)),            \
                       fmaxf(m4_, SA[3][3]));                               \
    rmax = redmax16_32(rmax);                                               \
    if (!__all(rmax <= m + 11.0f)) {                                        \
        const float nm_ = fmaxf(m, rmax);                                   \
        const float sc_f = EXP2F(m - nm_);                                  \
        m = nm_;                                                            \
        lsum *= sc_f;                                                       \
        float sc_r[4];                                                      \
        _Pragma("unroll")                                                   \
        for (int r = 0; r < 4; ++r) sc_r[r] = __shfl(sc_f, lg*4 + r);       \
        _Pragma("unroll")                                                   \
        for (int n = 0; n < 4; ++n)                                         \
        _Pragma("unroll")                                                   \
        for (int r = 0; r < 4; ++r) o[n][r] *= sc_r[r];                     \
    }                                                                       \
    _Pragma("unroll")                                                       \
    for (int n = 0; n < 4; ++n)                                             \
    _Pragma("unroll")                                                       \
    for (int r = 0; r < 4; ++r) SA[n][r] = EXP2F(SA[n][r] - m);             \
    /* pairwise sum tree, depth 4 */                                        \
    float s0_ = (SA[0][0]+SA[0][1]) + (SA[0][2]+SA[0][3]);                  \
    float s1_ = (SA[1][0]+SA[1][1]) + (SA[1][2]+SA[1][3]);                  \
    float s2_ = (SA[2][0]+SA[2][1]) + (SA[2][2]+SA[2][3]);                  \
    float s3_ = (SA[3][0]+SA[3][1]) + (SA[3][2]+SA[3][3]);                  \
    lsum += redsum16_32((s0_ + s1_) + (s2_ + s3_));                         \
    _Pragma("unroll")                                                       \
    for (int n = 0; n < 4; ++n) {                                           \
        union { short4v s; __hip_bfloat162 h[2]; } u;                       \
        u.h[0] = __float22bfloat162_rn(make_float2(SA[n][0], SA[n][1]));    \
        u.h[1] = __float22bfloat162_rn(make_float2(SA[n][2], SA[n][3]));    \
        pkp[n] = u.s;                                                       \
    } } while (0)

    // ---- prologue: stage tile 0; QK(0)+SM(0) while tile 1 stages ----
    LOAD_K(0);
    LOAD_V(0);
    WRITE_K(0);
    WRITE_V(0);
    __syncthreads();

    {
        if (ntile > 1) { LOAD_K(1); LOAD_V(1); }
        floatx4 sc[4];
        __builtin_amdgcn_s_setprio(1);
        QK_MFMA(sc, 0);
        __builtin_amdgcn_s_setprio(0);
        if (ntile > 1) { WRITE_K(1); WRITE_V(1); }
        SOFTMAX(sc, 0);
        if (ntile > 1) __syncthreads();
    }

    int vr = 0, vw = 2;                  // V buf of tile t-1 / tile t+1
    for (int t = 1; t < ntile; ++t) {
        const bool pf = (t + 1 < ntile);
        if (pf) { LOAD_K(t + 1); LOAD_V(t + 1); }

        floatx4 sc[4];
        __builtin_amdgcn_s_setprio(1);
        QK_MFMA(sc, t & 1);              // independent of...
        PV_MFMA(vr);                     // ...carried P of tile t-1
        __builtin_amdgcn_s_setprio(0);

        if (pf) { WRITE_K((t + 1) & 1); WRITE_V(vw); }
        SOFTMAX(sc, t);                  // terminal chain -> new pkp
        __syncthreads();                 // one barrier per tile

        vr = (vr == 2) ? 0 : vr + 1;
        vw = (vw == 2) ? 0 : vw + 1;
    }

    // ---- finish last tile's PV ----
    __builtin_amdgcn_s_setprio(1);
    PV_MFMA(vr);
    __builtin_amdgcn_s_setprio(0);

    // ---- epilogue: normalize and store (coalesced) ----
    const float inv = 1.0f / lsum;
    float inv_r[4];
#pragma unroll
    for (int r = 0; r < 4; ++r) inv_r[r] = __shfl(inv, lg*4 + r);

    float* Ob = out + (size_t)b * 65536;
#pragma unroll
    for (int n = 0; n < 4; ++n)
#pragma unroll
    for (int r = 0; r < 4; ++r) {
        const int q = qc*64 + w*16 + lg*4 + r;
        Ob[(size_t)q * 64 + n*16 + lr] = o[n][r] * inv_r[r];
    }
#undef LOAD_K
#undef LOAD_V
#undef WRITE_K
#undef WRITE_V
#undef QK_MFMA
#undef PV_MFMA
#undef SOFTMAX
}

extern "C" void kernel_launch(void* const* d_in, const int* in_sizes, int n_in,
                              void* d_out, int out_size, void* d_ws, size_t ws_size,
                              hipStream_t stream) {
    (void)in_sizes; (void)n_in; (void)d_ws; (void)ws_size; (void)out_size;
    const float* Q  = (const float*)d_in[0];
    const float* K  = (const float*)d_in[1];
    const float* V  = (const float*)d_in[2];
    const int*   vl = (const int*)d_in[3];
    float* O = (float*)d_out;
    attn_fwd<<<dim3(1024), dim3(256), 0, stream>>>(Q, K, V, vl, O);
}

// Round 12
// 37.424 us; speedup vs baseline: 1.5510x; 1.1902x over previous
//
#include <hip/hip_runtime.h>
#include <hip/hip_bf16.h>

#define NEG_BIG -1000000.0f

typedef __attribute__((ext_vector_type(8))) short short8;
typedef __attribute__((ext_vector_type(4))) short short4v;
typedef __attribute__((ext_vector_type(4))) float floatx4;

#if __has_builtin(__builtin_amdgcn_exp2f)
#define EXP2F(x) __builtin_amdgcn_exp2f(x)
#else
#define EXP2F(x) exp2f(x)
#endif

// K=16 bf16 MFMA (PV step): A[row=lane&15][k=4*(lane>>4)+j]
#if __has_builtin(__builtin_amdgcn_mfma_f32_16x16x16bf16_1k)
#define MFMA16(a, b, c) __builtin_amdgcn_mfma_f32_16x16x16bf16_1k(a, b, c, 0, 0, 0)
#else
static __device__ __forceinline__ floatx4 MFMA16_fn(short4v a, short4v b, floatx4 c) {
    floatx4 d;
    asm("v_mfma_f32_16x16x16_bf16 %0, %1, %2, %3\n\ts_nop 4"
        : "=v"(d) : "v"(a), "v"(b), "v"(c));
    return d;
}
#define MFMA16(a, b, c) MFMA16_fn(a, b, c)
#endif

// xor16 + xor32 wave reduction on the VALU (permlane swaps).
#if __has_builtin(__builtin_amdgcn_permlane16_swap) && __has_builtin(__builtin_amdgcn_permlane32_swap)
static __device__ __forceinline__ float redmax16_32(float x) {
    auto a = __builtin_amdgcn_permlane16_swap(__float_as_int(x), __float_as_int(x), false, false);
    x = fmaxf(__int_as_float(a[0]), __int_as_float(a[1]));
    auto b = __builtin_amdgcn_permlane32_swap(__float_as_int(x), __float_as_int(x), false, false);
    return fmaxf(__int_as_float(b[0]), __int_as_float(b[1]));
}
static __device__ __forceinline__ float redsum16_32(float x) {
    auto a = __builtin_amdgcn_permlane16_swap(__float_as_int(x), __float_as_int(x), false, false);
    x = __int_as_float(a[0]) + __int_as_float(a[1]);
    auto b = __builtin_amdgcn_permlane32_swap(__float_as_int(x), __float_as_int(x), false, false);
    return __int_as_float(b[0]) + __int_as_float(b[1]);
}
#else
static __device__ __forceinline__ float redmax16_32(float x) {
    x = fmaxf(x, __shfl_xor(x, 16));
    return fmaxf(x, __shfl_xor(x, 32));
}
static __device__ __forceinline__ float redsum16_32(float x) {
    x += __shfl_xor(x, 16);
    return x + __shfl_xor(x, 32);
}
#endif

static __device__ __forceinline__ unsigned short bf16u(float f) {
    union { __hip_bfloat16 h; unsigned short u; } c;
    c.h = __float2bfloat16(f);
    return c.u;
}

static __device__ __forceinline__ short8 pack8(float4 a, float4 b) {
    union { short8 s; __hip_bfloat162 h[4]; } u;
    u.h[0] = __float22bfloat162_rn(make_float2(a.x, a.y));
    u.h[1] = __float22bfloat162_rn(make_float2(a.z, a.w));
    u.h[2] = __float22bfloat162_rn(make_float2(b.x, b.y));
    u.h[3] = __float22bfloat162_rn(make_float2(b.z, b.w));
    return u.s;
}

// Block: 512 thr = 8 waves, 128 q-rows (wave owns one 16-row tile), ONE
// shared K/V staging pipeline -> per-batch K/V re-reads drop 16 -> 8 and
// chip-wide L2/L3 service volume halves (the r11-identified floor: every
// 64-row block re-pulled the batch's 512KB K/V through L2/L3, ~270 MB
// aggregate vs 34.5 TB/s L2 + slower L3).
// Grid: 512 blocks = 64 batches x 4... x 8 q-chunks, XCD-swizzled; LDS 40 KB
// + regs<=128 at launch_bounds(512,4) -> 2-4 blocks/CU, grid co-resident.
// Structure = r11: PV-deferred pipeline (carried bf16 P frags, 8 VGPRs),
// K double- / V triple-buffered, swapped QK^T (lane-local softmax),
// permlane reductions, deferred rescale (THR=11, exp2 domain), one
// barrier per tile.
__global__ __launch_bounds__(512, 4)
void attn_fwd(const float* __restrict__ Q, const float* __restrict__ K,
              const float* __restrict__ V, const int* __restrict__ vlen,
              float* __restrict__ out)
{
    // K_lds: elem (row,col) at row*64 + (col ^ ((row&7)*8))
    __shared__ __attribute__((aligned(16))) unsigned short K_lds[2][4096];
    // VT_lds: elem (dv,k) at dv*64 + (k ^ (((dv&7) ^ (dv>>3)) * 8))
    __shared__ __attribute__((aligned(16))) unsigned short VT_lds[3][4096];

    const int bid  = blockIdx.x;
    const int orig = (bid & 7) * 64 + (bid >> 3);   // bijective (512%8==0)
    const int b    = orig >> 3;                     // batch
    const int qc   = orig & 7;                      // q-chunk of 128 rows

    const int tid = threadIdx.x;
    const int l   = tid & 63;
    const int w   = tid >> 6;     // 0..7
    const int lr  = l & 15;
    const int lg  = l >> 4;

    const float* Qb = Q + (size_t)b * 65536;
    const float* Kb = K + (size_t)b * 65536;
    const float* Vb = V + (size_t)b * 65536;

    const int valid = vlen[b];
    const int kmax  = (valid == 0) ? 1024 : valid;   // all-masked -> uniform
    const int ntile = (kmax + 63) >> 6;

    // Q fragments (B-operand of swapped QK^T), pre-scaled log2(e)/8
    const float qscale = 0.18033688011112042f;
    short8 qf[2];
#pragma unroll
    for (int c = 0; c < 2; ++c) {
        const float* p = Qb + (size_t)(qc*128 + w*16 + lr) * 64 + c*32 + lg*8;
        float4 a = *(const float4*)p, bb = *(const float4*)(p + 4);
        a.x *= qscale; a.y *= qscale; a.z *= qscale; a.w *= qscale;
        bb.x *= qscale; bb.y *= qscale; bb.z *= qscale; bb.w *= qscale;
        qf[c] = pack8(a, bb);
    }

    floatx4 o[4];
#pragma unroll
    for (int n = 0; n < 4; ++n) o[n] = (floatx4){0.f, 0.f, 0.f, 0.f};
    float m = -INFINITY, lsum = 0.f;      // scalar state for q-row lr
    short4v pkp[4];                       // carried bf16 P frags of tile t-1

    // shared staging across 8 waves: thread stages 1 K-row-slice + 1 V-row-slice
    const int row   = tid >> 3;           // 0..63 (tile row)
    const int cbase = (tid & 7) * 8;      // col octet (floats)

    float4 kra[2], vra[2];

#define LOAD_K(T) do {                                                      \
    const float* pk_ = Kb + (size_t)((T)*64 + row) * 64 + cbase;            \
    kra[0] = *(const float4*)pk_;  kra[1] = *(const float4*)(pk_ + 4);      \
    } while (0)

#define LOAD_V(T) do {                                                      \
    const float* pv_ = Vb + (size_t)((T)*64 + row) * 64 + cbase;            \
    vra[0] = *(const float4*)pv_;  vra[1] = *(const float4*)(pv_ + 4);      \
    } while (0)

#define WRITE_K(B) do {                                                     \
    const int _fk = (row & 7) * 8;                                          \
    *(short8*)&K_lds[B][row*64 + (cbase ^ _fk)] = pack8(kra[0], kra[1]);    \
    } while (0)

#define WRITE_V(B) do {                                                     \
    _Pragma("unroll")                                                       \
    for (int j = 0; j < 8; ++j) {                                           \
        const int dv = cbase + j;                                           \
        const int fv = ((dv & 7) ^ (dv >> 3)) * 8;                          \
        VT_lds[B][dv*64 + (row ^ fv)] = bf16u(((const float*)&vra[j>>2])[j&3]); \
    } } while (0)

// QK^T of tile from K buffer KBUF into SA (no mask).
#define QK_MFMA(SA, KBUF) do {                                              \
    _Pragma("unroll")                                                       \
    for (int n = 0; n < 4; ++n) {                                           \
        const int kr_ = n*16 + lr;                                          \
        const int fk_ = (lr & 7) * 8;                                       \
        const short8 kf0 = *(const short8*)&K_lds[KBUF][kr_*64 + ((lg*8)      ^ fk_)]; \
        const short8 kf1 = *(const short8*)&K_lds[KBUF][kr_*64 + ((32 + lg*8) ^ fk_)]; \
        SA[n] = (floatx4){0.f, 0.f, 0.f, 0.f};                              \
        SA[n] = __builtin_amdgcn_mfma_f32_16x16x32_bf16(kf0, qf[0], SA[n], 0, 0, 0); \
        SA[n] = __builtin_amdgcn_mfma_f32_16x16x32_bf16(kf1, qf[1], SA[n], 0, 0, 0); \
    } } while (0)

// PV accumulate of the CARRIED tile from VT_lds[VBUF].
#define PV_MFMA(VBUF) do {                                                  \
    _Pragma("unroll")                                                       \
    for (int kc = 0; kc < 4; ++kc) {                                        \
        _Pragma("unroll")                                                   \
        for (int n2 = 0; n2 < 4; ++n2) {                                    \
            const int dv_ = n2*16 + lr;                                     \
            const int fv_ = ((dv_ & 7) ^ (dv_ >> 3)) * 8;                   \
            const short4v vf = *(const short4v*)&VT_lds[VBUF][dv_*64 + ((kc*16 + lg*4) ^ fv_)]; \
            o[n2] = MFMA16(pkp[kc], vf, o[n2]);                             \
        }                                                                   \
    } } while (0)

// mask + online softmax on SA (exp2 domain, deferred rescale) -> new pkp
#define SOFTMAX(SA, T) do {                                                 \
    const int _k0 = (T) * 64;                                               \
    if ((_k0 + 64) > valid) {                                               \
        const int kb_ = _k0 + lg*4;                                         \
        _Pragma("unroll")                                                   \
        for (int n = 0; n < 4; ++n)                                         \
        _Pragma("unroll")                                                   \
        for (int r = 0; r < 4; ++r)                                         \
            SA[n][r] = (kb_ + n*16 + r >= valid) ? NEG_BIG : SA[n][r];      \
    }                                                                       \
    /* balanced max tree (max3-fusable) */                                  \
    float m0_ = fmaxf(fmaxf(SA[0][0], SA[0][1]), SA[0][2]);                 \
    float m1_ = fmaxf(fmaxf(SA[0][3], SA[1][0]), SA[1][1]);                 \
    float m2_ = fmaxf(fmaxf(SA[1][2], SA[1][3]), SA[2][0]);                 \
    float m3_ = fmaxf(fmaxf(SA[2][1], SA[2][2]), SA[2][3]);                 \
    float m4_ = fmaxf(fmaxf(SA[3][0], SA[3][1]), SA[3][2]);                 \
    float rmax = fmaxf(fmaxf(fmaxf(m0_, m1_), fmaxf(m2_, m3_)),            \
                       fmaxf(m4_, SA[3][3]));                               \
    rmax = redmax16_32(rmax);                                               \
    if (!__all(rmax <= m + 11.0f)) {                                        \
        const float nm_ = fmaxf(m, rmax);                                   \
        const float sc_f = EXP2F(m - nm_);                                  \
        m = nm_;                                                            \
        lsum *= sc_f;                                                       \
        float sc_r[4];                                                      \
        _Pragma("unroll")                                                   \
        for (int r = 0; r < 4; ++r) sc_r[r] = __shfl(sc_f, lg*4 + r);       \
        _Pragma("unroll")                                                   \
        for (int n = 0; n < 4; ++n)                                         \
        _Pragma("unroll")                                                   \
        for (int r = 0; r < 4; ++r) o[n][r] *= sc_r[r];                     \
    }                                                                       \
    _Pragma("unroll")                                                       \
    for (int n = 0; n < 4; ++n)                                             \
    _Pragma("unroll")                                                       \
    for (int r = 0; r < 4; ++r) SA[n][r] = EXP2F(SA[n][r] - m);             \
    /* pairwise sum tree, depth 4 */                                        \
    float s0_ = (SA[0][0]+SA[0][1]) + (SA[0][2]+SA[0][3]);                  \
    float s1_ = (SA[1][0]+SA[1][1]) + (SA[1][2]+SA[1][3]);                  \
    float s2_ = (SA[2][0]+SA[2][1]) + (SA[2][2]+SA[2][3]);                  \
    float s3_ = (SA[3][0]+SA[3][1]) + (SA[3][2]+SA[3][3]);                  \
    lsum += redsum16_32((s0_ + s1_) + (s2_ + s3_));                         \
    _Pragma("unroll")                                                       \
    for (int n = 0; n < 4; ++n) {                                           \
        union { short4v s; __hip_bfloat162 h[2]; } u;                       \
        u.h[0] = __float22bfloat162_rn(make_float2(SA[n][0], SA[n][1]));    \
        u.h[1] = __float22bfloat162_rn(make_float2(SA[n][2], SA[n][3]));    \
        pkp[n] = u.s;                                                       \
    } } while (0)

    // ---- prologue: stage tile 0; QK(0)+SM(0) while tile 1 stages ----
    LOAD_K(0);
    LOAD_V(0);
    WRITE_K(0);
    WRITE_V(0);
    __syncthreads();

    {
        if (ntile > 1) { LOAD_K(1); LOAD_V(1); }
        floatx4 sc[4];
        __builtin_amdgcn_s_setprio(1);
        QK_MFMA(sc, 0);
        __builtin_amdgcn_s_setprio(0);
        if (ntile > 1) { WRITE_K(1); WRITE_V(1); }
        SOFTMAX(sc, 0);
        if (ntile > 1) __syncthreads();
    }

    int vr = 0, vw = 2;                  // V buf of tile t-1 / tile t+1
    for (int t = 1; t < ntile; ++t) {
        const bool pf = (t + 1 < ntile);
        if (pf) { LOAD_K(t + 1); LOAD_V(t + 1); }

        floatx4 sc[4];
        __builtin_amdgcn_s_setprio(1);
        QK_MFMA(sc, t & 1);              // independent of...
        PV_MFMA(vr);                     // ...carried P of tile t-1
        __builtin_amdgcn_s_setprio(0);

        if (pf) { WRITE_K((t + 1) & 1); WRITE_V(vw); }
        SOFTMAX(sc, t);                  // terminal chain -> new pkp
        __syncthreads();                 // one barrier per tile

        vr = (vr == 2) ? 0 : vr + 1;
        vw = (vw == 2) ? 0 : vw + 1;
    }

    // ---- finish last tile's PV ----
    __builtin_amdgcn_s_setprio(1);
    PV_MFMA(vr);
    __builtin_amdgcn_s_setprio(0);

    // ---- epilogue: normalize and store (coalesced) ----
    const float inv = 1.0f / lsum;
    float inv_r[4];
#pragma unroll
    for (int r = 0; r < 4; ++r) inv_r[r] = __shfl(inv, lg*4 + r);

    float* Ob = out + (size_t)b * 65536;
#pragma unroll
    for (int n = 0; n < 4; ++n)
#pragma unroll
    for (int r = 0; r < 4; ++r) {
        const int q = qc*128 + w*16 + lg*4 + r;
        Ob[(size_t)q * 64 + n*16 + lr] = o[n][r] * inv_r[r];
    }
#undef LOAD_K
#undef LOAD_V
#undef WRITE_K
#undef WRITE_V
#undef QK_MFMA
#undef PV_MFMA
#undef SOFTMAX
}

extern "C" void kernel_launch(void* const* d_in, const int* in_sizes, int n_in,
                              void* d_out, int out_size, void* d_ws, size_t ws_size,
                              hipStream_t stream) {
    (void)in_sizes; (void)n_in; (void)d_ws; (void)ws_size; (void)out_size;
    const float* Q  = (const float*)d_in[0];
    const float* K  = (const float*)d_in[1];
    const float* V  = (const float*)d_in[2];
    const int*   vl = (const int*)d_in[3];
    float* O = (float*)d_out;
    attn_fwd<<<dim3(512), dim3(512), 0, stream>>>(Q, K, V, vl, O);
}